// Round 4
// baseline (589.804 us; speedup 1.0000x reference)
//
#include <hip/hip_runtime.h>
#include <math.h>

typedef __bf16 bf16;
typedef __attribute__((ext_vector_type(8))) __bf16 bf16x8;
typedef __attribute__((ext_vector_type(4))) __bf16 bf16x4;
typedef __attribute__((ext_vector_type(4))) float f32x4;

#define NTOK 4096
#define DM   1024
#define NE   8      // routed experts
#define NEX  10     // + 2 shared halves (identity-routed, gate 1.0)
#define HE   704

// ---------------- workspace layout (bytes) ----------------
#define OFF_CNT   0u            // cnt[8]; pfx[11] at +32
#define OFF_TOK   256u          // [8][4096] int
#define OFF_WGT   131328u       // [8][4096] float
#define OFF_XB    262400u       // [4096][1024] bf16
#define OFF_W1T   8651008u      // [8][704][1024] bf16
#define OFF_W3T   20185344u
#define OFF_W2T   31719680u     // [8][1024][704] bf16
#define OFF_WS1T  43254016u     // [1408][1024] bf16 (= 2 pseudo-experts of 704 rows)
#define OFF_WS3T  46137600u
#define OFF_WS2T  49021184u     // [1024][1408] bf16 (k-halves = pseudo-expert W2)
#define OFF_ACT   51904768u     // [16384][704] bf16 (rows: pfx-compacted, 8192 routed + 8192 shared)
#define OFF_EIDS  74973440u     // [4096] int
#define OFF_GW    74989824u     // [4096] float2
// end: 75022592 (same high-water as previous rounds)

// async global->LDS, 16 B/lane: HW dest = wave-uniform base + lane*16 (m104/m108).
__device__ __forceinline__ void async_cp16(const bf16* g, bf16* l)
{
    __builtin_amdgcn_global_load_lds(
        (const __attribute__((address_space(1))) unsigned int*)g,
        (__attribute__((address_space(3))) unsigned int*)l, 16, 0, 0);
}

// ---------------- x -> bf16 ----------------
__global__ void cvt_x_kernel(const float* __restrict__ x, bf16* __restrict__ xb, int n4)
{
    int i = blockIdx.x * blockDim.x + threadIdx.x;
    if (i >= n4) return;
    float4 v = ((const float4*)x)[i];
    bf16x4 o;
    o[0] = (bf16)v.x; o[1] = (bf16)v.y; o[2] = (bf16)v.z; o[3] = (bf16)v.w;
    ((bf16x4*)xb)[i] = o;
}

// ---------------- all weight transposes fused: src [R][C] f32 -> dst [C][R] bf16 ----------------
__global__ __launch_bounds__(256) void transpose_all(
    const float* __restrict__ W1, const float* __restrict__ W3, const float* __restrict__ W2,
    const float* __restrict__ Ws1, const float* __restrict__ Ws3, const float* __restrict__ Ws2,
    bf16* __restrict__ w1t, bf16* __restrict__ w3t, bf16* __restrict__ w2t,
    bf16* __restrict__ ws1t, bf16* __restrict__ ws3t, bf16* __restrict__ ws2t)
{
    int id = blockIdx.x;
    const float* src; bf16* dst; int R, C, rt, ct;
    if (id < 5632)       { int t = id;         int e = t / 704, m = t % 704; R = 1024; C = 704;
                           src = W1 + (size_t)e * R * C;  dst = w1t + (size_t)e * R * C;  ct = m % 22; rt = m / 22; }
    else if (id < 11264) { int t = id - 5632;  int e = t / 704, m = t % 704; R = 1024; C = 704;
                           src = W3 + (size_t)e * R * C;  dst = w3t + (size_t)e * R * C;  ct = m % 22; rt = m / 22; }
    else if (id < 16896) { int t = id - 11264; int e = t / 704, m = t % 704; R = 704;  C = 1024;
                           src = W2 + (size_t)e * R * C;  dst = w2t + (size_t)e * R * C;  ct = m % 32; rt = m / 32; }
    else if (id < 18304) { int t = id - 16896; R = 1024; C = 1408; src = Ws1; dst = ws1t; ct = t % 44; rt = t / 44; }
    else if (id < 19712) { int t = id - 18304; R = 1024; C = 1408; src = Ws3; dst = ws3t; ct = t % 44; rt = t / 44; }
    else                 { int t = id - 19712; R = 1408; C = 1024; src = Ws2; dst = ws2t; ct = t % 32; rt = t / 32; }

    __shared__ float tl[32][33];
    int c0 = ct * 32, r0 = rt * 32;
    int row  = threadIdx.x >> 3;
    int col4 = (threadIdx.x & 7) * 4;
    float4 v = *(const float4*)&src[(size_t)(r0 + row) * C + c0 + col4];
    tl[row][col4 + 0] = v.x; tl[row][col4 + 1] = v.y;
    tl[row][col4 + 2] = v.z; tl[row][col4 + 3] = v.w;
    __syncthreads();
    bf16x4 o;
    o[0] = (bf16)tl[col4 + 0][row];
    o[1] = (bf16)tl[col4 + 1][row];
    o[2] = (bf16)tl[col4 + 2][row];
    o[3] = (bf16)tl[col4 + 3][row];
    *(bf16x4*)&dst[(size_t)(c0 + row) * R + r0 + col4] = o;
}

// ---------------- router pass 1: fp32 logits, softmax, top-2 per token ----------------
__global__ __launch_bounds__(256) void router_logits(
    const float* __restrict__ x, const float* __restrict__ Wg,
    int* __restrict__ eids, float2* __restrict__ gw)
{
    int n    = blockIdx.x * 4 + (threadIdx.x >> 6);
    int lane = threadIdx.x & 63;
    const float* xrow = x + (size_t)n * DM;
    float xr[16];
    #pragma unroll
    for (int j = 0; j < 16; j++) xr[j] = xrow[lane + 64 * j];
    float logit[NE];
    #pragma unroll
    for (int e = 0; e < NE; e++) {
        const float* wr = Wg + e * DM;
        float s = 0.f;
        #pragma unroll
        for (int j = 0; j < 16; j++) s += xr[j] * wr[lane + 64 * j];
        #pragma unroll
        for (int off = 32; off; off >>= 1) s += __shfl_xor(s, off, 64);
        logit[e] = s;
    }
    if (lane == 0) {
        int i0 = 0;
        #pragma unroll
        for (int e = 1; e < NE; e++) if (logit[e] > logit[i0]) i0 = e;
        int i1 = (i0 == 0) ? 1 : 0;
        #pragma unroll
        for (int e = 0; e < NE; e++) if (e != i0 && logit[e] > logit[i1]) i1 = e;
        float m = logit[0];
        #pragma unroll
        for (int e = 1; e < NE; e++) m = fmaxf(m, logit[e]);
        float denom = 0.f;
        #pragma unroll
        for (int e = 0; e < NE; e++) denom += expf(logit[e] - m);
        float g0 = expf(logit[i0] - m) / denom;
        float g1 = expf(logit[i1] - m) / denom;
        float inv = 1.f / (g0 + g1 + 1e-20f);
        eids[n] = i0 | (i1 << 16);
        gw[n] = make_float2(g0 * inv, g1 * inv);
    }
}

// ---------------- router pass 2: hierarchical list build ----------------
__global__ __launch_bounds__(128) void build_lists(
    const int* __restrict__ eids, const float2* __restrict__ gw,
    int* __restrict__ cnt, int* __restrict__ tok, float* __restrict__ wgt)
{
    __shared__ int lcnt[NE];
    __shared__ int gbase[NE];
    int t = threadIdx.x;
    int n = blockIdx.x * 128 + t;
    if (t < NE) lcnt[t] = 0;
    __syncthreads();
    int packed = eids[n];
    float2 w = gw[n];
    int e0 = packed & 0xffff, e1 = packed >> 16;
    int s0 = atomicAdd(&lcnt[e0], 1);
    int s1 = atomicAdd(&lcnt[e1], 1);
    __syncthreads();
    if (t < NE) gbase[t] = atomicAdd(&cnt[t], lcnt[t]);
    __syncthreads();
    int p0 = gbase[e0] + s0, p1 = gbase[e1] + s1;
    tok[e0 * NTOK + p0] = n; wgt[e0 * NTOK + p0] = w.x;
    tok[e1 * NTOK + p1] = n; wgt[e1 * NTOK + p1] = w.y;
}

__global__ void prefix_kernel(const int* __restrict__ cnt, int* __restrict__ pfx)
{
    if (threadIdx.x == 0) {
        int s = 0;
        for (int e = 0; e < NEX; e++) { pfx[e] = s; s += (e < NE) ? cnt[e] : NTOK; }
        pfx[NEX] = s;
    }
}

// ---------------- GEMM1: act = silu(A@W1) * (A@W3) over 10 experts ----------------
// Tile 128(m) x 64(h), BK=32. grid.x = m-tile (resident blocks share weight tile).
// LDS in FRAGMENT ORDER: group g (16 rows) at g*512, lane l holds row (l&15), k-chunk (l>>4).
// -> every ds_read_b128 is base + lane*16: zero bank conflicts.
__global__ __launch_bounds__(256) void gemm1_swiglu(
    const bf16* __restrict__ xb,
    const bf16* __restrict__ w1t, const bf16* __restrict__ w3t,
    const bf16* __restrict__ ws1t, const bf16* __restrict__ ws3t,
    bf16* __restrict__ act,
    const int* __restrict__ cnt, const int* __restrict__ pfx, const int* __restrict__ tok)
{
    int e = blockIdx.z;
    int count = (e < NE) ? cnt[e] : NTOK;
    int m0 = blockIdx.x * 128;
    if (m0 >= count) return;
    int h0 = blockIdx.y * 64;
    int base = pfx[e];
    const bf16 *B1, *B3;
    if (e < NE) { B1 = w1t + (size_t)e * HE * DM;        B3 = w3t + (size_t)e * HE * DM; }
    else        { B1 = ws1t + (size_t)(e - NE) * HE * DM; B3 = ws3t + (size_t)(e - NE) * HE * DM; }
    const int* tlist = (e < NE) ? tok + e * NTOK : nullptr;

    __shared__ bf16 As[128 * 32];
    __shared__ bf16 B1s[64 * 32];
    __shared__ bf16 B3s[64 * 32];

    int tid = threadIdx.x, w = tid >> 6, lane = tid & 63;
    int rl = lane & 15, ch = lane >> 4;       // fragment-order: row-in-group, k-chunk

    // A staging: wave w stages groups 2w, 2w+1 (rows m0+32w .. +31)
    int sA0 = m0 + 32 * w + rl, sA1 = sA0 + 16;
    int rA0 = tlist ? (sA0 < count ? tlist[sA0] : 0) : (sA0 < count ? sA0 : 0);
    int rA1 = tlist ? (sA1 < count ? tlist[sA1] : 0) : (sA1 < count ? sA1 : 0);
    const bf16* ga0 = xb + (size_t)rA0 * DM + ch * 8;
    const bf16* ga1 = xb + (size_t)rA1 * DM + ch * 8;
    // B staging: wave w stages group w of each (rows h0+16w .. +15)
    const bf16* gb1 = B1 + (size_t)(h0 + 16 * w + rl) * DM + ch * 8;
    const bf16* gb3 = B3 + (size_t)(h0 + 16 * w + rl) * DM + ch * 8;
    bf16* lA0 = As + (2 * w) * 512;
    bf16* lA1 = As + (2 * w + 1) * 512;
    bf16* lB1 = B1s + w * 512;
    bf16* lB3 = B3s + w * 512;

    int gA = (w & 1) * 4;        // A group base for this wave's m-rows
    int gB = (w >> 1) * 2;       // B group base for this wave's h-cols
    int wm = (w & 1) * 64, wn = (w >> 1) * 32;

    f32x4 acch[4][2], accg[4][2];
    #pragma unroll
    for (int i = 0; i < 4; i++)
        #pragma unroll
        for (int j = 0; j < 2; j++) {
            acch[i][j] = (f32x4){0.f, 0.f, 0.f, 0.f};
            accg[i][j] = (f32x4){0.f, 0.f, 0.f, 0.f};
        }

    for (int k0 = 0; k0 < DM; k0 += 32) {
        async_cp16(ga0, lA0);
        async_cp16(ga1, lA1);
        async_cp16(gb1, lB1);
        async_cp16(gb3, lB3);
        ga0 += 32; ga1 += 32; gb1 += 32; gb3 += 32;
        __syncthreads();
        bf16x8 af[4], b1f[2], b3f[2];
        #pragma unroll
        for (int i = 0; i < 4; i++) af[i] = *(const bf16x8*)(As + (gA + i) * 512 + lane * 8);
        #pragma unroll
        for (int j = 0; j < 2; j++) {
            b1f[j] = *(const bf16x8*)(B1s + (gB + j) * 512 + lane * 8);
            b3f[j] = *(const bf16x8*)(B3s + (gB + j) * 512 + lane * 8);
        }
        #pragma unroll
        for (int i = 0; i < 4; i++)
            #pragma unroll
            for (int j = 0; j < 2; j++) {
                acch[i][j] = __builtin_amdgcn_mfma_f32_16x16x32_bf16(af[i], b1f[j], acch[i][j], 0, 0, 0);
                accg[i][j] = __builtin_amdgcn_mfma_f32_16x16x32_bf16(af[i], b3f[j], accg[i][j], 0, 0, 0);
            }
        __syncthreads();
    }

    #pragma unroll
    for (int i = 0; i < 4; i++)
        #pragma unroll
        for (int j = 0; j < 2; j++)
            #pragma unroll
            for (int r = 0; r < 4; r++) {
                int row = wm + i * 16 + ch * 4 + r;     // C/D: row = quad*4 + reg
                int s2 = m0 + row;
                if (s2 < count) {
                    float hv = acch[i][j][r], gv = accg[i][j][r];
                    float a = hv / (1.f + expf(-hv)) * gv;
                    act[(size_t)(base + s2) * HE + h0 + wn + j * 16 + rl] = (bf16)a;
                }
            }
}

// ---------------- GEMM2: out += gate * (act @ W2) over 10 experts (all-atomic) ----------------
// Tile 128(m) x 128(d), BK=32, K = 704 uniform. grid.x = m-tile.
__global__ __launch_bounds__(256) void gemm2_combine(
    const bf16* __restrict__ act,
    const bf16* __restrict__ w2t, const bf16* __restrict__ ws2t,
    float* __restrict__ out,
    const int* __restrict__ cnt, const int* __restrict__ pfx,
    const int* __restrict__ tok, const float* __restrict__ wgt)
{
    int e = blockIdx.z;
    int count = (e < NE) ? cnt[e] : NTOK;
    int m0 = blockIdx.x * 128;
    if (m0 >= count) return;
    int d0 = blockIdx.y * 128;
    int base = pfx[e];
    const bf16* B; size_t ldB;
    if (e < NE) { B = w2t + (size_t)e * DM * HE; ldB = HE; }
    else        { B = ws2t + (size_t)(e - NE) * HE; ldB = 2 * HE; }  // ws2t [1024][1408], k-half
    const int*   tlist = (e < NE) ? tok + e * NTOK : nullptr;
    const float* wl    = (e < NE) ? wgt + e * NTOK : nullptr;

    __shared__ bf16 As[128 * 32];
    __shared__ bf16 Bs[128 * 32];

    int tid = threadIdx.x, w = tid >> 6, lane = tid & 63;
    int rl = lane & 15, ch = lane >> 4;

    int sA0 = m0 + 32 * w + rl, sA1 = sA0 + 16;
    int a0 = (sA0 < count) ? (base + sA0) : base;
    int a1 = (sA1 < count) ? (base + sA1) : base;
    const bf16* ga0 = act + (size_t)a0 * HE + ch * 8;
    const bf16* ga1 = act + (size_t)a1 * HE + ch * 8;
    const bf16* gb0 = B + (size_t)(d0 + 32 * w + rl) * ldB + ch * 8;
    const bf16* gb1 = B + (size_t)(d0 + 32 * w + 16 + rl) * ldB + ch * 8;
    bf16* lA0 = As + (2 * w) * 512;
    bf16* lA1 = As + (2 * w + 1) * 512;
    bf16* lB0 = Bs + (2 * w) * 512;
    bf16* lB1 = Bs + (2 * w + 1) * 512;

    int gA = (w & 1) * 4, gB = (w >> 1) * 4;
    int wm = (w & 1) * 64, wn = (w >> 1) * 64;

    f32x4 acc[4][4];
    #pragma unroll
    for (int i = 0; i < 4; i++)
        #pragma unroll
        for (int j = 0; j < 4; j++) acc[i][j] = (f32x4){0.f, 0.f, 0.f, 0.f};

    for (int k0 = 0; k0 < HE; k0 += 32) {
        async_cp16(ga0, lA0);
        async_cp16(ga1, lA1);
        async_cp16(gb0, lB0);
        async_cp16(gb1, lB1);
        ga0 += 32; ga1 += 32; gb0 += 32; gb1 += 32;
        __syncthreads();
        bf16x8 af[4], bf_[4];
        #pragma unroll
        for (int i = 0; i < 4; i++) af[i]  = *(const bf16x8*)(As + (gA + i) * 512 + lane * 8);
        #pragma unroll
        for (int j = 0; j < 4; j++) bf_[j] = *(const bf16x8*)(Bs + (gB + j) * 512 + lane * 8);
        #pragma unroll
        for (int i = 0; i < 4; i++)
            #pragma unroll
            for (int j = 0; j < 4; j++)
                acc[i][j] = __builtin_amdgcn_mfma_f32_16x16x32_bf16(af[i], bf_[j], acc[i][j], 0, 0, 0);
        __syncthreads();
    }

    #pragma unroll
    for (int i = 0; i < 4; i++)
        #pragma unroll
        for (int j = 0; j < 4; j++)
            #pragma unroll
            for (int r = 0; r < 4; r++) {
                int row = wm + i * 16 + ch * 4 + r;
                int s2 = m0 + row;
                if (s2 < count) {
                    int   t  = tlist ? tlist[s2] : s2;
                    float wt = wl ? wl[s2] : 1.0f;
                    int col = d0 + wn + j * 16 + rl;
                    atomicAdd(&out[(size_t)t * DM + col], wt * acc[i][j][r]);
                }
            }
}

extern "C" void kernel_launch(void* const* d_in, const int* in_sizes, int n_in,
                              void* d_out, int out_size, void* d_ws, size_t ws_size,
                              hipStream_t stream)
{
    const float* x   = (const float*)d_in[0];
    const float* Wg  = (const float*)d_in[1];
    const float* W1  = (const float*)d_in[2];
    const float* W3  = (const float*)d_in[3];
    const float* W2  = (const float*)d_in[4];
    const float* Ws1 = (const float*)d_in[5];
    const float* Ws3 = (const float*)d_in[6];
    const float* Ws2 = (const float*)d_in[7];
    float* out = (float*)d_out;
    char*  ws  = (char*)d_ws;

    int*    cnt  = (int*)(ws + OFF_CNT);
    int*    pfx  = (int*)(ws + OFF_CNT + 32);
    int*    tok  = (int*)(ws + OFF_TOK);
    float*  wgt  = (float*)(ws + OFF_WGT);
    bf16*   xb   = (bf16*)(ws + OFF_XB);
    bf16*   w1t  = (bf16*)(ws + OFF_W1T);
    bf16*   w3t  = (bf16*)(ws + OFF_W3T);
    bf16*   w2t  = (bf16*)(ws + OFF_W2T);
    bf16*   ws1t = (bf16*)(ws + OFF_WS1T);
    bf16*   ws3t = (bf16*)(ws + OFF_WS3T);
    bf16*   ws2t = (bf16*)(ws + OFF_WS2T);
    bf16*   act  = (bf16*)(ws + OFF_ACT);
    int*    eids = (int*)(ws + OFF_EIDS);
    float2* gw   = (float2*)(ws + OFF_GW);

    hipMemsetAsync(ws, 0, 256, stream);
    hipMemsetAsync(out, 0, (size_t)NTOK * DM * sizeof(float), stream);

    cvt_x_kernel<<<4096, 256, 0, stream>>>(x, xb, NTOK * DM / 4);
    transpose_all<<<21120, 256, 0, stream>>>(W1, W3, W2, Ws1, Ws3, Ws2,
                                             w1t, w3t, w2t, ws1t, ws3t, ws2t);
    router_logits<<<1024, 256, 0, stream>>>(x, Wg, eids, gw);
    build_lists<<<32, 128, 0, stream>>>(eids, gw, cnt, tok, wgt);
    prefix_kernel<<<1, 64, 0, stream>>>(cnt, pfx);

    // unified up-proj+swiglu over 10 experts (x = m-tile so co-resident blocks share weights)
    gemm1_swiglu<<<dim3(32, HE / 64, NEX), 256, 0, stream>>>(
        xb, w1t, w3t, ws1t, ws3t, act, cnt, pfx, tok);
    // unified down-proj, gate-weighted atomic accumulate
    gemm2_combine<<<dim3(32, DM / 128, NEX), 256, 0, stream>>>(
        act, w2t, ws2t, out, cnt, pfx, tok, wgt);
}

// Round 6
// 344.807 us; speedup vs baseline: 1.7105x; 1.7105x over previous
//
#include <hip/hip_runtime.h>
#include <math.h>

typedef __bf16 bf16;
typedef __attribute__((ext_vector_type(8))) __bf16 bf16x8;
typedef __attribute__((ext_vector_type(4))) __bf16 bf16x4;
typedef __attribute__((ext_vector_type(4))) float f32x4;

#define NTOK 4096
#define DM   1024
#define NE   8      // routed experts
#define NEX  10     // + 2 shared halves (identity-routed, gate 1.0)
#define HE   704

// ---------------- workspace layout (bytes) — identical high-water to r3/r4 (~75 MB) ----------
#define OFF_CNT   0u            // cnt[8]; pfx[11] at +32
#define OFF_TOK   256u          // [8][4096] int
#define OFF_WGT   131328u       // [8][4096] float
#define OFF_XB    262400u       // [4096][1024] bf16 row-major
#define OFF_W1T   8651008u      // [8] swizzled [44][32][64][8] bf16
#define OFF_W3T   20185344u
#define OFF_W2T   31719680u     // [8] swizzled [64][22][64][8] bf16
#define OFF_WS1T  43254016u     // [2] swizzled [44][32][64][8]
#define OFF_WS3T  46137600u
#define OFF_WS2T  49021184u     // [2] swizzled [64][22][64][8]
#define OFF_ACT   51904768u     // [16384][704] bf16 row-major (pfx-compacted)
#define OFF_EIDS  74973440u     // [4096] int
#define OFF_GW    74989824u     // [4096] float2

// async global->LDS, 16 B/lane: HW dest = wave-uniform base + lane*16 (m104/m108).
__device__ __forceinline__ void async_cp16(const bf16* g, bf16* l)
{
    __builtin_amdgcn_global_load_lds(
        (const __attribute__((address_space(1))) unsigned int*)g,
        (__attribute__((address_space(3))) unsigned int*)l, 16, 0, 0);
}

// ---------------- x -> bf16 (row-major) ----------------
__global__ void cvt_x_kernel(const float* __restrict__ x, bf16* __restrict__ xb, int n4)
{
    int i = blockIdx.x * blockDim.x + threadIdx.x;
    if (i >= n4) return;
    float4 v = ((const float4*)x)[i];
    bf16x4 o;
    o[0] = (bf16)v.x; o[1] = (bf16)v.y; o[2] = (bf16)v.z; o[3] = (bf16)v.w;
    ((bf16x4*)xb)[i] = o;
}

// ---------------- weight transpose+convert -> fragment-swizzled 1KB blocks ----------------
// Swizzled layout per expert: block (g, kt) of 512 elems; unit lane=(c<<4)|r holds
// rows r=n&15 of n-group g, k-chunk c (8 elems). cp16 of one block = lane*16B: contiguous.
__global__ __launch_bounds__(256) void transpose_all(
    const float* __restrict__ W1, const float* __restrict__ W3, const float* __restrict__ W2,
    const float* __restrict__ Ws1, const float* __restrict__ Ws3, const float* __restrict__ Ws2,
    bf16* __restrict__ w1t, bf16* __restrict__ w3t, bf16* __restrict__ w2t,
    bf16* __restrict__ ws1t, bf16* __restrict__ ws3t, bf16* __restrict__ ws2t)
{
    int id = blockIdx.x;
    const float* src; bf16* dst; int C, rt, ct, nkt;
    if (id < 5632)       { int t = id;         int e = t / 704, m = t % 704; C = 704;
                           src = W1 + (size_t)e * 1024 * 704;  dst = w1t + (size_t)e * 720896;
                           ct = m % 22; rt = m / 22; nkt = 32; }
    else if (id < 11264) { int t = id - 5632;  int e = t / 704, m = t % 704; C = 704;
                           src = W3 + (size_t)e * 1024 * 704;  dst = w3t + (size_t)e * 720896;
                           ct = m % 22; rt = m / 22; nkt = 32; }
    else if (id < 16896) { int t = id - 11264; int e = t / 704, m = t % 704; C = 1024;
                           src = W2 + (size_t)e * 704 * 1024;  dst = w2t + (size_t)e * 720896;
                           ct = m % 32; rt = m / 32; nkt = 22; }
    else if (id < 18304) { int t = id - 16896; C = 1408; src = Ws1;
                           ct = t % 44; rt = t / 44; nkt = 32;
                           int ep = (ct >= 22) ? 1 : 0; ct -= 22 * ep;
                           src += (size_t)704 * ep;             // FIX r5: column offset for n-half
                           dst = ws1t + (size_t)ep * 720896; }
    else if (id < 19712) { int t = id - 18304; C = 1408; src = Ws3;
                           ct = t % 44; rt = t / 44; nkt = 32;
                           int ep = (ct >= 22) ? 1 : 0; ct -= 22 * ep;
                           src += (size_t)704 * ep;             // FIX r5: column offset for n-half
                           dst = ws3t + (size_t)ep * 720896; }
    else                 { int t = id - 19712; C = 1024; src = Ws2;
                           ct = t % 32; rt = t / 32; nkt = 22;
                           int ep = (rt >= 22) ? 1 : 0; rt -= 22 * ep;
                           src += (size_t)704 * 1024 * ep;      // row offset for k-half (correct)
                           dst = ws2t + (size_t)ep * 720896; }

    __shared__ float tl[32][33];
    int c0 = ct * 32, r0 = rt * 32;          // r = k dim, c = n dim (src [K][N] row-major)
    int row  = threadIdx.x >> 3;             // 0..31
    int col4 = (threadIdx.x & 7) * 4;        // 0..28
    float4 v = *(const float4*)&src[(size_t)(r0 + row) * C + c0 + col4];
    tl[row][col4 + 0] = v.x; tl[row][col4 + 1] = v.y;
    tl[row][col4 + 2] = v.z; tl[row][col4 + 3] = v.w;
    __syncthreads();
    // thread writes n = c0+row, k = r0+col4..+3 (same 8-chunk: col4%8 in {0,4})
    int n  = c0 + row;
    int ng = n >> 4, nr = n & 15;
    int kt = rt;
    int cc = col4 >> 3, j = col4 & 7;
    bf16x4 o;
    o[0] = (bf16)tl[col4 + 0][row];
    o[1] = (bf16)tl[col4 + 1][row];
    o[2] = (bf16)tl[col4 + 2][row];
    o[3] = (bf16)tl[col4 + 3][row];
    *(bf16x4*)&dst[(size_t)(((ng * nkt + kt) << 9) + (((cc << 4) | nr) << 3) + j)] = o;
}

// ---------------- router pass 1: fp32 logits, softmax, top-2 per token ----------------
__global__ __launch_bounds__(256) void router_logits(
    const float* __restrict__ x, const float* __restrict__ Wg,
    int* __restrict__ eids, float2* __restrict__ gw)
{
    int n    = blockIdx.x * 4 + (threadIdx.x >> 6);
    int lane = threadIdx.x & 63;
    const float* xrow = x + (size_t)n * DM;
    float xr[16];
    #pragma unroll
    for (int j = 0; j < 16; j++) xr[j] = xrow[lane + 64 * j];
    float logit[NE];
    #pragma unroll
    for (int e = 0; e < NE; e++) {
        const float* wr = Wg + e * DM;
        float s = 0.f;
        #pragma unroll
        for (int j = 0; j < 16; j++) s += xr[j] * wr[lane + 64 * j];
        #pragma unroll
        for (int off = 32; off; off >>= 1) s += __shfl_xor(s, off, 64);
        logit[e] = s;
    }
    if (lane == 0) {
        int i0 = 0;
        #pragma unroll
        for (int e = 1; e < NE; e++) if (logit[e] > logit[i0]) i0 = e;
        int i1 = (i0 == 0) ? 1 : 0;
        #pragma unroll
        for (int e = 0; e < NE; e++) if (e != i0 && logit[e] > logit[i1]) i1 = e;
        float m = logit[0];
        #pragma unroll
        for (int e = 1; e < NE; e++) m = fmaxf(m, logit[e]);
        float denom = 0.f;
        #pragma unroll
        for (int e = 0; e < NE; e++) denom += expf(logit[e] - m);
        float g0 = expf(logit[i0] - m) / denom;
        float g1 = expf(logit[i1] - m) / denom;
        float inv = 1.f / (g0 + g1 + 1e-20f);
        eids[n] = i0 | (i1 << 16);
        gw[n] = make_float2(g0 * inv, g1 * inv);
    }
}

// ---------------- router pass 2: hierarchical list build ----------------
__global__ __launch_bounds__(128) void build_lists(
    const int* __restrict__ eids, const float2* __restrict__ gw,
    int* __restrict__ cnt, int* __restrict__ tok, float* __restrict__ wgt)
{
    __shared__ int lcnt[NE];
    __shared__ int gbase[NE];
    int t = threadIdx.x;
    int n = blockIdx.x * 128 + t;
    if (t < NE) lcnt[t] = 0;
    __syncthreads();
    int packed = eids[n];
    float2 w = gw[n];
    int e0 = packed & 0xffff, e1 = packed >> 16;
    int s0 = atomicAdd(&lcnt[e0], 1);
    int s1 = atomicAdd(&lcnt[e1], 1);
    __syncthreads();
    if (t < NE) gbase[t] = atomicAdd(&cnt[t], lcnt[t]);
    __syncthreads();
    int p0 = gbase[e0] + s0, p1 = gbase[e1] + s1;
    tok[e0 * NTOK + p0] = n; wgt[e0 * NTOK + p0] = w.x;
    tok[e1 * NTOK + p1] = n; wgt[e1 * NTOK + p1] = w.y;
}

__global__ void prefix_kernel(const int* __restrict__ cnt, int* __restrict__ pfx)
{
    if (threadIdx.x == 0) {
        int s = 0;
        for (int e = 0; e < NEX; e++) { pfx[e] = s; s += (e < NE) ? cnt[e] : NTOK; }
        pfx[NEX] = s;
    }
}

// A-side XOR swizzle: LDS 16B-unit u in a 16-row group holds (row u>>2, chunk (u&3)^((u>>3)&3)).
// Staging lane l (coalesced: 4 lanes per 64B row-segment) reads chunk (l&3)^((l>>3)&3).
// Fragment read unit for (r,c): 4r + (c^((r>>1)&3)) -> 2-way bank aliasing (free).

// ---------------- GEMM1: act = silu(A@W1) * (A@W3) over 10 experts ----------------
// Tile 128(m) x 64(h), BK=32. B from pre-swizzled weights (contiguous 1KB cp16, seq reads).
__global__ __launch_bounds__(256) void gemm1_swiglu(
    const bf16* __restrict__ xb,
    const bf16* __restrict__ w1t, const bf16* __restrict__ w3t,
    const bf16* __restrict__ ws1t, const bf16* __restrict__ ws3t,
    bf16* __restrict__ act,
    const int* __restrict__ cnt, const int* __restrict__ pfx, const int* __restrict__ tok)
{
    int e = blockIdx.z;
    int count = (e < NE) ? cnt[e] : NTOK;
    int m0 = blockIdx.y * 128;
    if (m0 >= count) return;
    int h0 = blockIdx.x * 64;
    int base = pfx[e];
    const bf16 *B1, *B3;
    if (e < NE) { B1 = w1t + (size_t)e * 720896;        B3 = w3t + (size_t)e * 720896; }
    else        { B1 = ws1t + (size_t)(e - NE) * 720896; B3 = ws3t + (size_t)(e - NE) * 720896; }
    const int* tlist = (e < NE) ? tok + e * NTOK : nullptr;

    __shared__ bf16 As[8 * 512];
    __shared__ bf16 B1s[4 * 512];
    __shared__ bf16 B3s[4 * 512];

    int tid = threadIdx.x, w = tid >> 6, lane = tid & 63;

    // A staging (gathered rows, coalesced + XOR chunk)
    int r3 = lane >> 2;
    int cx = (lane & 3) ^ ((r3 >> 1) & 3);
    int sA0 = m0 + 32 * w + r3, sA1 = sA0 + 16;
    int rA0 = tlist ? (sA0 < count ? tlist[sA0] : 0) : (sA0 < count ? sA0 : 0);
    int rA1 = tlist ? (sA1 < count ? tlist[sA1] : 0) : (sA1 < count ? sA1 : 0);
    const bf16* ga0 = xb + (size_t)rA0 * DM + cx * 8;
    const bf16* ga1 = xb + (size_t)rA1 * DM + cx * 8;
    bf16* lA0 = As + (2 * w) * 512;
    bf16* lA1 = As + (2 * w + 1) * 512;
    // B staging (pre-swizzled: contiguous 1KB per group x ktile)
    const bf16* gb1 = B1 + ((size_t)((h0 >> 4) + w) * 32) * 512 + lane * 8;
    const bf16* gb3 = B3 + ((size_t)((h0 >> 4) + w) * 32) * 512 + lane * 8;
    bf16* lB1 = B1s + w * 512;
    bf16* lB3 = B3s + w * 512;

    int rl = lane & 15, ch = lane >> 4;
    int uA = 4 * rl + (ch ^ ((rl >> 1) & 3));        // A fragment unit (XOR layout)
    int gA = (w & 1) * 4;
    int gB = (w >> 1) * 2;
    int wm = (w & 1) * 64, wn = (w >> 1) * 32;

    f32x4 acch[4][2], accg[4][2];
    #pragma unroll
    for (int i = 0; i < 4; i++)
        #pragma unroll
        for (int j = 0; j < 2; j++) {
            acch[i][j] = (f32x4){0.f, 0.f, 0.f, 0.f};
            accg[i][j] = (f32x4){0.f, 0.f, 0.f, 0.f};
        }

    for (int k0 = 0; k0 < DM; k0 += 32) {
        async_cp16(ga0, lA0);
        async_cp16(ga1, lA1);
        async_cp16(gb1, lB1);
        async_cp16(gb3, lB3);
        ga0 += 32; ga1 += 32; gb1 += 512; gb3 += 512;
        __syncthreads();
        bf16x8 af[4], b1f[2], b3f[2];
        #pragma unroll
        for (int i = 0; i < 4; i++) af[i] = *(const bf16x8*)(As + (gA + i) * 512 + uA * 8);
        #pragma unroll
        for (int j = 0; j < 2; j++) {
            b1f[j] = *(const bf16x8*)(B1s + (gB + j) * 512 + lane * 8);
            b3f[j] = *(const bf16x8*)(B3s + (gB + j) * 512 + lane * 8);
        }
        #pragma unroll
        for (int i = 0; i < 4; i++)
            #pragma unroll
            for (int j = 0; j < 2; j++) {
                acch[i][j] = __builtin_amdgcn_mfma_f32_16x16x32_bf16(af[i], b1f[j], acch[i][j], 0, 0, 0);
                accg[i][j] = __builtin_amdgcn_mfma_f32_16x16x32_bf16(af[i], b3f[j], accg[i][j], 0, 0, 0);
            }
        __syncthreads();
    }

    #pragma unroll
    for (int i = 0; i < 4; i++)
        #pragma unroll
        for (int j = 0; j < 2; j++)
            #pragma unroll
            for (int r = 0; r < 4; r++) {
                int row = wm + i * 16 + ch * 4 + r;     // C/D: row = quad*4 + reg
                int s2 = m0 + row;
                if (s2 < count) {
                    float hv = acch[i][j][r], gv = accg[i][j][r];
                    float a = hv / (1.f + expf(-hv)) * gv;
                    act[(size_t)(base + s2) * HE + h0 + wn + j * 16 + rl] = (bf16)a;
                }
            }
}

// ---------------- GEMM2: out += gate * (act @ W2) over 10 experts (all-atomic) ----------------
// Tile 128(m) x 128(d), BK=32, K=704. act row-major via XOR staging; W2 pre-swizzled.
__global__ __launch_bounds__(256) void gemm2_combine(
    const bf16* __restrict__ act,
    const bf16* __restrict__ w2t, const bf16* __restrict__ ws2t,
    float* __restrict__ out,
    const int* __restrict__ cnt, const int* __restrict__ pfx,
    const int* __restrict__ tok, const float* __restrict__ wgt)
{
    int e = blockIdx.z;
    int count = (e < NE) ? cnt[e] : NTOK;
    int m0 = blockIdx.y * 128;
    if (m0 >= count) return;
    int d0 = blockIdx.x * 128;
    int base = pfx[e];
    const bf16* B = (e < NE) ? w2t + (size_t)e * 720896 : ws2t + (size_t)(e - NE) * 720896;
    const int*   tlist = (e < NE) ? tok + e * NTOK : nullptr;
    const float* wl    = (e < NE) ? wgt + e * NTOK : nullptr;

    __shared__ bf16 As[8 * 512];
    __shared__ bf16 Bs[8 * 512];

    int tid = threadIdx.x, w = tid >> 6, lane = tid & 63;

    int r3 = lane >> 2;
    int cx = (lane & 3) ^ ((r3 >> 1) & 3);
    int sA0 = m0 + 32 * w + r3, sA1 = sA0 + 16;
    int a0 = (sA0 < count) ? (base + sA0) : base;
    int a1 = (sA1 < count) ? (base + sA1) : base;
    const bf16* ga0 = act + (size_t)a0 * HE + cx * 8;
    const bf16* ga1 = act + (size_t)a1 * HE + cx * 8;
    bf16* lA0 = As + (2 * w) * 512;
    bf16* lA1 = As + (2 * w + 1) * 512;
    // B: d-groups (d0>>4 + 2w), (d0>>4 + 2w + 1); 22 k-tiles
    const bf16* gb0 = B + ((size_t)((d0 >> 4) + 2 * w) * 22) * 512 + lane * 8;
    const bf16* gb1 = B + ((size_t)((d0 >> 4) + 2 * w + 1) * 22) * 512 + lane * 8;
    bf16* lB0 = Bs + (2 * w) * 512;
    bf16* lB1 = Bs + (2 * w + 1) * 512;

    int rl = lane & 15, ch = lane >> 4;
    int uA = 4 * rl + (ch ^ ((rl >> 1) & 3));
    int gA = (w & 1) * 4, gB = (w >> 1) * 4;
    int wm = (w & 1) * 64, wn = (w >> 1) * 64;

    f32x4 acc[4][4];
    #pragma unroll
    for (int i = 0; i < 4; i++)
        #pragma unroll
        for (int j = 0; j < 4; j++) acc[i][j] = (f32x4){0.f, 0.f, 0.f, 0.f};

    for (int k0 = 0; k0 < HE; k0 += 32) {
        async_cp16(ga0, lA0);
        async_cp16(ga1, lA1);
        async_cp16(gb0, lB0);
        async_cp16(gb1, lB1);
        ga0 += 32; ga1 += 32; gb0 += 512; gb1 += 512;
        __syncthreads();
        bf16x8 af[4], bf_[4];
        #pragma unroll
        for (int i = 0; i < 4; i++) af[i]  = *(const bf16x8*)(As + (gA + i) * 512 + uA * 8);
        #pragma unroll
        for (int j = 0; j < 4; j++) bf_[j] = *(const bf16x8*)(Bs + (gB + j) * 512 + lane * 8);
        #pragma unroll
        for (int i = 0; i < 4; i++)
            #pragma unroll
            for (int j = 0; j < 4; j++)
                acc[i][j] = __builtin_amdgcn_mfma_f32_16x16x32_bf16(af[i], bf_[j], acc[i][j], 0, 0, 0);
        __syncthreads();
    }

    #pragma unroll
    for (int i = 0; i < 4; i++)
        #pragma unroll
        for (int j = 0; j < 4; j++)
            #pragma unroll
            for (int r = 0; r < 4; r++) {
                int row = wm + i * 16 + ch * 4 + r;
                int s2 = m0 + row;
                if (s2 < count) {
                    int   t  = tlist ? tlist[s2] : s2;
                    float wt = wl ? wl[s2] : 1.0f;
                    int col = d0 + wn + j * 16 + rl;
                    atomicAdd(&out[(size_t)t * DM + col], wt * acc[i][j][r]);
                }
            }
}

extern "C" void kernel_launch(void* const* d_in, const int* in_sizes, int n_in,
                              void* d_out, int out_size, void* d_ws, size_t ws_size,
                              hipStream_t stream)
{
    const float* x   = (const float*)d_in[0];
    const float* Wg  = (const float*)d_in[1];
    const float* W1  = (const float*)d_in[2];
    const float* W3  = (const float*)d_in[3];
    const float* W2  = (const float*)d_in[4];
    const float* Ws1 = (const float*)d_in[5];
    const float* Ws3 = (const float*)d_in[6];
    const float* Ws2 = (const float*)d_in[7];
    float* out = (float*)d_out;
    char*  ws  = (char*)d_ws;

    int*    cnt  = (int*)(ws + OFF_CNT);
    int*    pfx  = (int*)(ws + OFF_CNT + 32);
    int*    tok  = (int*)(ws + OFF_TOK);
    float*  wgt  = (float*)(ws + OFF_WGT);
    bf16*   xb   = (bf16*)(ws + OFF_XB);
    bf16*   w1t  = (bf16*)(ws + OFF_W1T);
    bf16*   w3t  = (bf16*)(ws + OFF_W3T);
    bf16*   w2t  = (bf16*)(ws + OFF_W2T);
    bf16*   ws1t = (bf16*)(ws + OFF_WS1T);
    bf16*   ws3t = (bf16*)(ws + OFF_WS3T);
    bf16*   ws2t = (bf16*)(ws + OFF_WS2T);
    bf16*   act  = (bf16*)(ws + OFF_ACT);
    int*    eids = (int*)(ws + OFF_EIDS);
    float2* gw   = (float2*)(ws + OFF_GW);

    hipMemsetAsync(ws, 0, 256, stream);
    hipMemsetAsync(out, 0, (size_t)NTOK * DM * sizeof(float), stream);

    cvt_x_kernel<<<4096, 256, 0, stream>>>(x, xb, NTOK * DM / 4);
    transpose_all<<<21120, 256, 0, stream>>>(W1, W3, W2, Ws1, Ws3, Ws2,
                                             w1t, w3t, w2t, ws1t, ws3t, ws2t);
    router_logits<<<1024, 256, 0, stream>>>(x, Wg, eids, gw);
    build_lists<<<32, 128, 0, stream>>>(eids, gw, cnt, tok, wgt);
    prefix_kernel<<<1, 64, 0, stream>>>(cnt, pfx);

    // unified up-proj+swiglu over 10 experts (x = h-tile fastest, as round 3)
    gemm1_swiglu<<<dim3(HE / 64, 32, NEX), 256, 0, stream>>>(
        xb, w1t, w3t, ws1t, ws3t, act, cnt, pfx, tok);
    // unified down-proj, gate-weighted atomic accumulate
    gemm2_combine<<<dim3(DM / 128, 32, NEX), 256, 0, stream>>>(
        act, w2t, ws2t, out, cnt, pfx, tok, wgt);
}

// Round 7
// 324.125 us; speedup vs baseline: 1.8197x; 1.0638x over previous
//
#include <hip/hip_runtime.h>
#include <math.h>

typedef __bf16 bf16;
typedef __attribute__((ext_vector_type(8))) __bf16 bf16x8;
typedef __attribute__((ext_vector_type(4))) __bf16 bf16x4;
typedef __attribute__((ext_vector_type(4))) float f32x4;

#define NTOK 4096
#define DM   1024
#define NE   8      // routed experts
#define NEX  10     // + 2 shared halves (identity-routed)
#define HE   704

// ---------------- workspace layout (bytes) — high-water ~75 MB ----------
#define OFF_CNT   0u            // cnt[8]; pfx[11] at +32
#define OFF_TOK   256u          // [8][4096] int
#define OFF_WGT   131328u       // [8][4096] float
#define OFF_XB    262400u       // [4096][1024] bf16 row-major
#define OFF_W1T   8651008u      // [8] swizzled [44][32][64][8] bf16   (reused as yr after gemm1)
#define OFF_W3T   20185344u
#define OFF_W2T   31719680u     // [8] swizzled [64][22][64][8] bf16
#define OFF_WS1T  43254016u     // [2] swizzled [44][32][64][8]
#define OFF_WS3T  46137600u
#define OFF_WS2T  49021184u     // [2] swizzled [64][22][64][8]
#define OFF_ACT   51904768u     // [16384][704] bf16 row-major (pfx-compacted)
#define OFF_EIDS  74973440u     // [4096] int
#define OFF_GW    74989824u     // [4096] float2
#define OFF_SLOT  75022592u     // [4096] int2  ((e<<16)|pos per routed assignment)
#define OFF_YR    OFF_W1T       // [8192][1024] bf16 routed weighted partials (aliases w1t/w3t)

// async global->LDS, 16 B/lane: HW dest = wave-uniform base + lane*16 (m104/m108).
__device__ __forceinline__ void async_cp16(const bf16* g, bf16* l)
{
    __builtin_amdgcn_global_load_lds(
        (const __attribute__((address_space(1))) unsigned int*)g,
        (__attribute__((address_space(3))) unsigned int*)l, 16, 0, 0);
}

// ---------------- x -> bf16 (row-major) ----------------
__global__ void cvt_x_kernel(const float* __restrict__ x, bf16* __restrict__ xb, int n4)
{
    int i = blockIdx.x * blockDim.x + threadIdx.x;
    if (i >= n4) return;
    float4 v = ((const float4*)x)[i];
    bf16x4 o;
    o[0] = (bf16)v.x; o[1] = (bf16)v.y; o[2] = (bf16)v.z; o[3] = (bf16)v.w;
    ((bf16x4*)xb)[i] = o;
}

// ---------------- weight transpose+convert -> fragment-swizzled 1KB blocks ----------------
__global__ __launch_bounds__(256) void transpose_all(
    const float* __restrict__ W1, const float* __restrict__ W3, const float* __restrict__ W2,
    const float* __restrict__ Ws1, const float* __restrict__ Ws3, const float* __restrict__ Ws2,
    bf16* __restrict__ w1t, bf16* __restrict__ w3t, bf16* __restrict__ w2t,
    bf16* __restrict__ ws1t, bf16* __restrict__ ws3t, bf16* __restrict__ ws2t)
{
    int id = blockIdx.x;
    const float* src; bf16* dst; int C, rt, ct, nkt;
    if (id < 5632)       { int t = id;         int e = t / 704, m = t % 704; C = 704;
                           src = W1 + (size_t)e * 1024 * 704;  dst = w1t + (size_t)e * 720896;
                           ct = m % 22; rt = m / 22; nkt = 32; }
    else if (id < 11264) { int t = id - 5632;  int e = t / 704, m = t % 704; C = 704;
                           src = W3 + (size_t)e * 1024 * 704;  dst = w3t + (size_t)e * 720896;
                           ct = m % 22; rt = m / 22; nkt = 32; }
    else if (id < 16896) { int t = id - 11264; int e = t / 704, m = t % 704; C = 1024;
                           src = W2 + (size_t)e * 704 * 1024;  dst = w2t + (size_t)e * 720896;
                           ct = m % 32; rt = m / 32; nkt = 22; }
    else if (id < 18304) { int t = id - 16896; C = 1408; src = Ws1;
                           ct = t % 44; rt = t / 44; nkt = 32;
                           int ep = (ct >= 22) ? 1 : 0; ct -= 22 * ep;
                           src += (size_t)704 * ep;
                           dst = ws1t + (size_t)ep * 720896; }
    else if (id < 19712) { int t = id - 18304; C = 1408; src = Ws3;
                           ct = t % 44; rt = t / 44; nkt = 32;
                           int ep = (ct >= 22) ? 1 : 0; ct -= 22 * ep;
                           src += (size_t)704 * ep;
                           dst = ws3t + (size_t)ep * 720896; }
    else                 { int t = id - 19712; C = 1024; src = Ws2;
                           ct = t % 32; rt = t / 32; nkt = 22;
                           int ep = (rt >= 22) ? 1 : 0; rt -= 22 * ep;
                           src += (size_t)704 * 1024 * ep;
                           dst = ws2t + (size_t)ep * 720896; }

    __shared__ float tl[32][33];
    int c0 = ct * 32, r0 = rt * 32;          // r = k dim, c = n dim (src [K][N] row-major)
    int row  = threadIdx.x >> 3;
    int col4 = (threadIdx.x & 7) * 4;
    float4 v = *(const float4*)&src[(size_t)(r0 + row) * C + c0 + col4];
    tl[row][col4 + 0] = v.x; tl[row][col4 + 1] = v.y;
    tl[row][col4 + 2] = v.z; tl[row][col4 + 3] = v.w;
    __syncthreads();
    int n  = c0 + row;
    int ng = n >> 4, nr = n & 15;
    int kt = rt;
    int cc = col4 >> 3, j = col4 & 7;
    bf16x4 o;
    o[0] = (bf16)tl[col4 + 0][row];
    o[1] = (bf16)tl[col4 + 1][row];
    o[2] = (bf16)tl[col4 + 2][row];
    o[3] = (bf16)tl[col4 + 3][row];
    *(bf16x4*)&dst[(size_t)(((ng * nkt + kt) << 9) + (((cc << 4) | nr) << 3) + j)] = o;
}

// ---------------- router pass 1: fp32 logits, softmax, top-2 per token ----------------
__global__ __launch_bounds__(256) void router_logits(
    const float* __restrict__ x, const float* __restrict__ Wg,
    int* __restrict__ eids, float2* __restrict__ gw)
{
    int n    = blockIdx.x * 4 + (threadIdx.x >> 6);
    int lane = threadIdx.x & 63;
    const float* xrow = x + (size_t)n * DM;
    float xr[16];
    #pragma unroll
    for (int j = 0; j < 16; j++) xr[j] = xrow[lane + 64 * j];
    float logit[NE];
    #pragma unroll
    for (int e = 0; e < NE; e++) {
        const float* wr = Wg + e * DM;
        float s = 0.f;
        #pragma unroll
        for (int j = 0; j < 16; j++) s += xr[j] * wr[lane + 64 * j];
        #pragma unroll
        for (int off = 32; off; off >>= 1) s += __shfl_xor(s, off, 64);
        logit[e] = s;
    }
    if (lane == 0) {
        int i0 = 0;
        #pragma unroll
        for (int e = 1; e < NE; e++) if (logit[e] > logit[i0]) i0 = e;
        int i1 = (i0 == 0) ? 1 : 0;
        #pragma unroll
        for (int e = 0; e < NE; e++) if (e != i0 && logit[e] > logit[i1]) i1 = e;
        float m = logit[0];
        #pragma unroll
        for (int e = 1; e < NE; e++) m = fmaxf(m, logit[e]);
        float denom = 0.f;
        #pragma unroll
        for (int e = 0; e < NE; e++) denom += expf(logit[e] - m);
        float g0 = expf(logit[i0] - m) / denom;
        float g1 = expf(logit[i1] - m) / denom;
        float inv = 1.f / (g0 + g1 + 1e-20f);
        eids[n] = i0 | (i1 << 16);
        gw[n] = make_float2(g0 * inv, g1 * inv);
    }
}

// ---------------- router pass 2: list build + per-token slot record ----------------
__global__ __launch_bounds__(128) void build_lists(
    const int* __restrict__ eids, const float2* __restrict__ gw,
    int* __restrict__ cnt, int* __restrict__ tok, float* __restrict__ wgt,
    int2* __restrict__ slots)
{
    __shared__ int lcnt[NE];
    __shared__ int gbase[NE];
    int t = threadIdx.x;
    int n = blockIdx.x * 128 + t;
    if (t < NE) lcnt[t] = 0;
    __syncthreads();
    int packed = eids[n];
    float2 w = gw[n];
    int e0 = packed & 0xffff, e1 = packed >> 16;
    int s0 = atomicAdd(&lcnt[e0], 1);
    int s1 = atomicAdd(&lcnt[e1], 1);
    __syncthreads();
    if (t < NE) gbase[t] = atomicAdd(&cnt[t], lcnt[t]);
    __syncthreads();
    int p0 = gbase[e0] + s0, p1 = gbase[e1] + s1;
    tok[e0 * NTOK + p0] = n; wgt[e0 * NTOK + p0] = w.x;
    tok[e1 * NTOK + p1] = n; wgt[e1 * NTOK + p1] = w.y;
    slots[n] = make_int2((e0 << 16) | p0, (e1 << 16) | p1);
}

__global__ void prefix_kernel(const int* __restrict__ cnt, int* __restrict__ pfx)
{
    if (threadIdx.x == 0) {
        int s = 0;
        for (int e = 0; e < NEX; e++) { pfx[e] = s; s += (e < NE) ? cnt[e] : NTOK; }
        pfx[NEX] = s;
    }
}

// A-side XOR swizzle (zero-conflict, coalesced staging): see r5 notes.

// ---------------- GEMM1: act = silu(A@W1) * (A@W3) over 10 experts ----------------
__global__ __launch_bounds__(256) void gemm1_swiglu(
    const bf16* __restrict__ xb,
    const bf16* __restrict__ w1t, const bf16* __restrict__ w3t,
    const bf16* __restrict__ ws1t, const bf16* __restrict__ ws3t,
    bf16* __restrict__ act,
    const int* __restrict__ cnt, const int* __restrict__ pfx, const int* __restrict__ tok)
{
    int e = blockIdx.z;
    int count = (e < NE) ? cnt[e] : NTOK;
    int m0 = blockIdx.y * 128;
    if (m0 >= count) return;
    int h0 = blockIdx.x * 64;
    int base = pfx[e];
    const bf16 *B1, *B3;
    if (e < NE) { B1 = w1t + (size_t)e * 720896;        B3 = w3t + (size_t)e * 720896; }
    else        { B1 = ws1t + (size_t)(e - NE) * 720896; B3 = ws3t + (size_t)(e - NE) * 720896; }
    const int* tlist = (e < NE) ? tok + e * NTOK : nullptr;

    __shared__ bf16 As[8 * 512];
    __shared__ bf16 B1s[4 * 512];
    __shared__ bf16 B3s[4 * 512];

    int tid = threadIdx.x, w = tid >> 6, lane = tid & 63;

    int r3 = lane >> 2;
    int cx = (lane & 3) ^ ((r3 >> 1) & 3);
    int sA0 = m0 + 32 * w + r3, sA1 = sA0 + 16;
    int rA0 = tlist ? (sA0 < count ? tlist[sA0] : 0) : (sA0 < count ? sA0 : 0);
    int rA1 = tlist ? (sA1 < count ? tlist[sA1] : 0) : (sA1 < count ? sA1 : 0);
    const bf16* ga0 = xb + (size_t)rA0 * DM + cx * 8;
    const bf16* ga1 = xb + (size_t)rA1 * DM + cx * 8;
    bf16* lA0 = As + (2 * w) * 512;
    bf16* lA1 = As + (2 * w + 1) * 512;
    const bf16* gb1 = B1 + ((size_t)((h0 >> 4) + w) * 32) * 512 + lane * 8;
    const bf16* gb3 = B3 + ((size_t)((h0 >> 4) + w) * 32) * 512 + lane * 8;
    bf16* lB1 = B1s + w * 512;
    bf16* lB3 = B3s + w * 512;

    int rl = lane & 15, ch = lane >> 4;
    int uA = 4 * rl + (ch ^ ((rl >> 1) & 3));
    int gA = (w & 1) * 4;
    int gB = (w >> 1) * 2;
    int wm = (w & 1) * 64, wn = (w >> 1) * 32;

    f32x4 acch[4][2], accg[4][2];
    #pragma unroll
    for (int i = 0; i < 4; i++)
        #pragma unroll
        for (int j = 0; j < 2; j++) {
            acch[i][j] = (f32x4){0.f, 0.f, 0.f, 0.f};
            accg[i][j] = (f32x4){0.f, 0.f, 0.f, 0.f};
        }

    for (int k0 = 0; k0 < DM; k0 += 32) {
        async_cp16(ga0, lA0);
        async_cp16(ga1, lA1);
        async_cp16(gb1, lB1);
        async_cp16(gb3, lB3);
        ga0 += 32; ga1 += 32; gb1 += 512; gb3 += 512;
        __syncthreads();
        bf16x8 af[4], b1f[2], b3f[2];
        #pragma unroll
        for (int i = 0; i < 4; i++) af[i] = *(const bf16x8*)(As + (gA + i) * 512 + uA * 8);
        #pragma unroll
        for (int j = 0; j < 2; j++) {
            b1f[j] = *(const bf16x8*)(B1s + (gB + j) * 512 + lane * 8);
            b3f[j] = *(const bf16x8*)(B3s + (gB + j) * 512 + lane * 8);
        }
        #pragma unroll
        for (int i = 0; i < 4; i++)
            #pragma unroll
            for (int j = 0; j < 2; j++) {
                acch[i][j] = __builtin_amdgcn_mfma_f32_16x16x32_bf16(af[i], b1f[j], acch[i][j], 0, 0, 0);
                accg[i][j] = __builtin_amdgcn_mfma_f32_16x16x32_bf16(af[i], b3f[j], accg[i][j], 0, 0, 0);
            }
        __syncthreads();
    }

    #pragma unroll
    for (int i = 0; i < 4; i++)
        #pragma unroll
        for (int j = 0; j < 2; j++)
            #pragma unroll
            for (int r = 0; r < 4; r++) {
                int row = wm + i * 16 + ch * 4 + r;
                int s2 = m0 + row;
                if (s2 < count) {
                    float hv = acch[i][j][r], gv = accg[i][j][r];
                    float a = hv / (1.f + expf(-hv)) * gv;
                    act[(size_t)(base + s2) * HE + h0 + wn + j * 16 + rl] = (bf16)a;
                }
            }
}

// ---------------- GEMM2 routed: yr[slot] = bf16(gate * act@W2), plain stores ----------------
__global__ __launch_bounds__(256) void gemm2_routed(
    const bf16* __restrict__ act,
    const bf16* __restrict__ w2t,
    bf16* __restrict__ yr,
    const int* __restrict__ cnt, const int* __restrict__ pfx,
    const float* __restrict__ wgt)
{
    int e = blockIdx.z;
    int count = cnt[e];
    int m0 = blockIdx.y * 128;
    if (m0 >= count) return;
    int d0 = blockIdx.x * 128;
    int base = pfx[e];
    const bf16* B = w2t + (size_t)e * 720896;
    const float* wl = wgt + e * NTOK;

    __shared__ bf16 As[8 * 512];
    __shared__ bf16 Bs[8 * 512];

    int tid = threadIdx.x, w = tid >> 6, lane = tid & 63;

    int r3 = lane >> 2;
    int cx = (lane & 3) ^ ((r3 >> 1) & 3);
    int sA0 = m0 + 32 * w + r3, sA1 = sA0 + 16;
    int a0 = (sA0 < count) ? (base + sA0) : base;
    int a1 = (sA1 < count) ? (base + sA1) : base;
    const bf16* ga0 = act + (size_t)a0 * HE + cx * 8;
    const bf16* ga1 = act + (size_t)a1 * HE + cx * 8;
    bf16* lA0 = As + (2 * w) * 512;
    bf16* lA1 = As + (2 * w + 1) * 512;
    const bf16* gb0 = B + ((size_t)((d0 >> 4) + 2 * w) * 22) * 512 + lane * 8;
    const bf16* gb1 = B + ((size_t)((d0 >> 4) + 2 * w + 1) * 22) * 512 + lane * 8;
    bf16* lB0 = Bs + (2 * w) * 512;
    bf16* lB1 = Bs + (2 * w + 1) * 512;

    int rl = lane & 15, ch = lane >> 4;
    int uA = 4 * rl + (ch ^ ((rl >> 1) & 3));
    int gA = (w & 1) * 4, gB = (w >> 1) * 4;
    int wm = (w & 1) * 64, wn = (w >> 1) * 64;

    f32x4 acc[4][4];
    #pragma unroll
    for (int i = 0; i < 4; i++)
        #pragma unroll
        for (int j = 0; j < 4; j++) acc[i][j] = (f32x4){0.f, 0.f, 0.f, 0.f};

    for (int kt = 0; kt < 22; kt++) {
        async_cp16(ga0, lA0);
        async_cp16(ga1, lA1);
        async_cp16(gb0, lB0);
        async_cp16(gb1, lB1);
        ga0 += 32; ga1 += 32; gb0 += 512; gb1 += 512;
        __syncthreads();
        bf16x8 af[4], bf_[4];
        #pragma unroll
        for (int i = 0; i < 4; i++) af[i]  = *(const bf16x8*)(As + (gA + i) * 512 + uA * 8);
        #pragma unroll
        for (int j = 0; j < 4; j++) bf_[j] = *(const bf16x8*)(Bs + (gB + j) * 512 + lane * 8);
        #pragma unroll
        for (int i = 0; i < 4; i++)
            #pragma unroll
            for (int j = 0; j < 4; j++)
                acc[i][j] = __builtin_amdgcn_mfma_f32_16x16x32_bf16(af[i], bf_[j], acc[i][j], 0, 0, 0);
        __syncthreads();
    }

    #pragma unroll
    for (int i = 0; i < 4; i++) {
        #pragma unroll
        for (int r = 0; r < 4; r++) {
            int row = wm + i * 16 + ch * 4 + r;
            int s2 = m0 + row;
            if (s2 < count) {
                float wt = wl[s2];
                bf16* yrow = yr + (size_t)(base + s2) * DM + d0 + wn;
                #pragma unroll
                for (int j = 0; j < 4; j++)
                    yrow[j * 16 + rl] = (bf16)(wt * acc[i][j][r]);
            }
        }
    }
}

// ---------------- GEMM2 shared: out[n] = act_sh @ Ws2 (K=1408 via two halves), dense ----------
__global__ __launch_bounds__(256) void gemm2_shared(
    const bf16* __restrict__ act,
    const bf16* __restrict__ ws2t,
    float* __restrict__ out)
{
    int m0 = blockIdx.y * 128;
    int d0 = blockIdx.x * 128;

    __shared__ bf16 As[8 * 512];
    __shared__ bf16 Bs[8 * 512];

    int tid = threadIdx.x, w = tid >> 6, lane = tid & 63;

    int r3 = lane >> 2;
    int cx = (lane & 3) ^ ((r3 >> 1) & 3);
    int sA0 = m0 + 32 * w + r3, sA1 = sA0 + 16;
    bf16* lA0 = As + (2 * w) * 512;
    bf16* lA1 = As + (2 * w + 1) * 512;
    bf16* lB0 = Bs + (2 * w) * 512;
    bf16* lB1 = Bs + (2 * w + 1) * 512;

    int rl = lane & 15, ch = lane >> 4;
    int uA = 4 * rl + (ch ^ ((rl >> 1) & 3));
    int gA = (w & 1) * 4, gB = (w >> 1) * 4;
    int wm = (w & 1) * 64, wn = (w >> 1) * 64;

    f32x4 acc[4][4];
    #pragma unroll
    for (int i = 0; i < 4; i++)
        #pragma unroll
        for (int j = 0; j < 4; j++) acc[i][j] = (f32x4){0.f, 0.f, 0.f, 0.f};

    #pragma unroll
    for (int h = 0; h < 2; h++) {
        int rowbase = 8192 + 4096 * h;          // pfx[8]=8192, pfx[9]=12288 (identity-routed)
        const bf16* ga0 = act + (size_t)(rowbase + sA0) * HE + cx * 8;
        const bf16* ga1 = act + (size_t)(rowbase + sA1) * HE + cx * 8;
        const bf16* B = ws2t + (size_t)h * 720896;
        const bf16* gb0 = B + ((size_t)((d0 >> 4) + 2 * w) * 22) * 512 + lane * 8;
        const bf16* gb1 = B + ((size_t)((d0 >> 4) + 2 * w + 1) * 22) * 512 + lane * 8;
        for (int kt = 0; kt < 22; kt++) {
            async_cp16(ga0, lA0);
            async_cp16(ga1, lA1);
            async_cp16(gb0, lB0);
            async_cp16(gb1, lB1);
            ga0 += 32; ga1 += 32; gb0 += 512; gb1 += 512;
            __syncthreads();
            bf16x8 af[4], bf_[4];
            #pragma unroll
            for (int i = 0; i < 4; i++) af[i]  = *(const bf16x8*)(As + (gA + i) * 512 + uA * 8);
            #pragma unroll
            for (int j = 0; j < 4; j++) bf_[j] = *(const bf16x8*)(Bs + (gB + j) * 512 + lane * 8);
            #pragma unroll
            for (int i = 0; i < 4; i++)
                #pragma unroll
                for (int j = 0; j < 4; j++)
                    acc[i][j] = __builtin_amdgcn_mfma_f32_16x16x32_bf16(af[i], bf_[j], acc[i][j], 0, 0, 0);
            __syncthreads();
        }
    }

    #pragma unroll
    for (int i = 0; i < 4; i++)
        #pragma unroll
        for (int r = 0; r < 4; r++) {
            int row = wm + i * 16 + ch * 4 + r;
            float* orow = out + (size_t)(m0 + row) * DM + d0 + wn;
            #pragma unroll
            for (int j = 0; j < 4; j++)
                orow[j * 16 + rl] = acc[i][j][r];
        }
}

// ---------------- fuse: out[n] += yr[slot0] + yr[slot1] ----------------
__global__ __launch_bounds__(256) void fuse_add(
    const bf16* __restrict__ yr, const int2* __restrict__ slots,
    const int* __restrict__ pfx, float* __restrict__ out)
{
    int n = blockIdx.x;
    int2 s = slots[n];
    int slot0 = pfx[s.x >> 16] + (s.x & 0xffff);
    int slot1 = pfx[s.y >> 16] + (s.y & 0xffff);
    const bf16* y0 = yr + (size_t)slot0 * DM;
    const bf16* y1 = yr + (size_t)slot1 * DM;
    float* orow = out + (size_t)n * DM;
    int d = threadIdx.x * 4;
    bf16x4 a = *(const bf16x4*)(y0 + d);
    bf16x4 b = *(const bf16x4*)(y1 + d);
    float4 o = *(float4*)(orow + d);
    o.x += (float)a[0] + (float)b[0];
    o.y += (float)a[1] + (float)b[1];
    o.z += (float)a[2] + (float)b[2];
    o.w += (float)a[3] + (float)b[3];
    *(float4*)(orow + d) = o;
}

extern "C" void kernel_launch(void* const* d_in, const int* in_sizes, int n_in,
                              void* d_out, int out_size, void* d_ws, size_t ws_size,
                              hipStream_t stream)
{
    const float* x   = (const float*)d_in[0];
    const float* Wg  = (const float*)d_in[1];
    const float* W1  = (const float*)d_in[2];
    const float* W3  = (const float*)d_in[3];
    const float* W2  = (const float*)d_in[4];
    const float* Ws1 = (const float*)d_in[5];
    const float* Ws3 = (const float*)d_in[6];
    const float* Ws2 = (const float*)d_in[7];
    float* out = (float*)d_out;
    char*  ws  = (char*)d_ws;

    int*    cnt   = (int*)(ws + OFF_CNT);
    int*    pfx   = (int*)(ws + OFF_CNT + 32);
    int*    tok   = (int*)(ws + OFF_TOK);
    float*  wgt   = (float*)(ws + OFF_WGT);
    bf16*   xb    = (bf16*)(ws + OFF_XB);
    bf16*   w1t   = (bf16*)(ws + OFF_W1T);
    bf16*   w3t   = (bf16*)(ws + OFF_W3T);
    bf16*   w2t   = (bf16*)(ws + OFF_W2T);
    bf16*   ws1t  = (bf16*)(ws + OFF_WS1T);
    bf16*   ws3t  = (bf16*)(ws + OFF_WS3T);
    bf16*   ws2t  = (bf16*)(ws + OFF_WS2T);
    bf16*   act   = (bf16*)(ws + OFF_ACT);
    int*    eids  = (int*)(ws + OFF_EIDS);
    float2* gw    = (float2*)(ws + OFF_GW);
    int2*   slots = (int2*)(ws + OFF_SLOT);
    bf16*   yr    = (bf16*)(ws + OFF_YR);     // aliases w1t/w3t (dead after gemm1)

    hipMemsetAsync(ws, 0, 256, stream);

    cvt_x_kernel<<<4096, 256, 0, stream>>>(x, xb, NTOK * DM / 4);
    transpose_all<<<21120, 256, 0, stream>>>(W1, W3, W2, Ws1, Ws3, Ws2,
                                             w1t, w3t, w2t, ws1t, ws3t, ws2t);
    router_logits<<<1024, 256, 0, stream>>>(x, Wg, eids, gw);
    build_lists<<<32, 128, 0, stream>>>(eids, gw, cnt, tok, wgt, slots);
    prefix_kernel<<<1, 64, 0, stream>>>(cnt, pfx);

    gemm1_swiglu<<<dim3(HE / 64, 32, NEX), 256, 0, stream>>>(
        xb, w1t, w3t, ws1t, ws3t, act, cnt, pfx, tok);

    // routed down-proj -> per-slot weighted bf16 partials (no atomics)
    gemm2_routed<<<dim3(DM / 128, 32, NE), 256, 0, stream>>>(
        act, w2t, yr, cnt, pfx, wgt);
    // shared down-proj -> dense fp32 out (plain stores; no memset needed)
    gemm2_shared<<<dim3(DM / 128, NTOK / 128, 1), 256, 0, stream>>>(
        act, ws2t, out);
    // combine
    fuse_add<<<NTOK, 256, 0, stream>>>(yr, slots, pfx, out);
}